// Round 4
// baseline (467.279 us; speedup 1.0000x reference)
//
#include <hip/hip_runtime.h>
#include <hip/hip_bf16.h>

#define N_NODES 100000
#define N_FEATS 512
#define HIDDEN 64
#define NUM_SAMPLES 5
#define NUM_CLASSES 16
#define BATCH 16384

typedef __attribute__((ext_vector_type(8))) short bf16x8;
typedef __attribute__((ext_vector_type(4))) float f32x4;

static __device__ __forceinline__ float bf2f(short s) {
    unsigned int u = ((unsigned int)(unsigned short)s) << 16;
    return __builtin_bit_cast(float, u);
}
static __device__ __forceinline__ short f2bf(float v) {
    __hip_bfloat16 b = __float2bfloat16(v);
    return *reinterpret_cast<short*>(&b);
}
static __device__ __forceinline__ int clampi(int v) {
    return ((unsigned)v < (unsigned)N_NODES) ? v : 0;
}

// prep: (a) convert w1 [64*1024] fp32 -> bf16 into ws; (b) block 0 detects whether
// `nodes` is int64 (all sampled odd int32 words zero) and writes flag.
__global__ __launch_bounds__(256) void prep(const float* __restrict__ w1f,
                                            short* __restrict__ w1b,
                                            const int* __restrict__ nodes_i32,
                                            int* __restrict__ flag) {
    const int t = blockIdx.x * 256 + threadIdx.x;
    if (t < 64 * 1024) w1b[t] = f2bf(w1f[t]);
    if (blockIdx.x == 0 && threadIdx.x == 0) {
        int odd_nonzero = 0;
        for (int i = 0; i < 64; i++) {
            if (nodes_i32[2 * i + 1] != 0) odd_nonzero++;
        }
        *flag = (odd_nonzero == 0) ? 1 : 0;  // 1 => nodes is int64
    }
}

// Kernel A: PQ[n][c] (bf16): c<64 -> feat @ W1a^T ; c in [64,128) -> feat @ W1b^T
// feat fp32 [100000][512]; w1b bf16 [64][1024]; col c -> h=c&63, part=c>>6.
__global__ __launch_bounds__(256) void pq_gemm(const float* __restrict__ feat,
                                               const short* __restrict__ w1b,
                                               short* __restrict__ PQ) {
    const int wave = threadIdx.x >> 6;
    const int lane = threadIdx.x & 63;
    const int quad = lane >> 4;
    const int l16  = lane & 15;
    const int r0   = blockIdx.x * 64 + wave * 16;

    int rA = r0 + l16;
    if (rA >= N_NODES) rA = N_NODES - 1;

    f32x4 acc[8];
#pragma unroll
    for (int i = 0; i < 8; i++) acc[i] = (f32x4){0.f, 0.f, 0.f, 0.f};

    const float* aptr = feat + (size_t)rA * N_FEATS + quad * 8;

    for (int k0 = 0; k0 < N_FEATS; k0 += 32) {
        f32x4 a0 = *reinterpret_cast<const f32x4*>(aptr + k0);
        f32x4 a1 = *reinterpret_cast<const f32x4*>(aptr + k0 + 4);
        bf16x8 afrag;
#pragma unroll
        for (int j = 0; j < 4; j++) { afrag[j] = f2bf(a0[j]); afrag[4 + j] = f2bf(a1[j]); }
#pragma unroll
        for (int nb = 0; nb < 8; nb++) {
            const int cn = nb * 16 + l16;
            const int h = cn & 63;
            const int part = cn >> 6;
            bf16x8 bfrag = *reinterpret_cast<const bf16x8*>(
                w1b + (size_t)h * 1024 + part * 512 + quad * 8 + k0);
            acc[nb] = __builtin_amdgcn_mfma_f32_16x16x32_bf16(afrag, bfrag, acc[nb], 0, 0, 0);
        }
    }

    // C/D layout (16x16x32): col(N) = lane&15, row(M) = quad*4 + reg
#pragma unroll
    for (int nb = 0; nb < 8; nb++) {
        const int cn = nb * 16 + l16;
#pragma unroll
        for (int r = 0; r < 4; r++) {
            const int row = r0 + quad * 4 + r;
            if (row < N_NODES) PQ[(size_t)row * 128 + cn] = f2bf(acc[nb][r]);
        }
    }
}

// Kernel B: h1[n][h] = relu(P[n][h] + 0.2*sum_s Q[neigh[n][s]][h]) IN-PLACE into
// PQ[n*128+h]. Writes only cols 0..63; Q reads only cols 64..127 -> race-free.
__global__ __launch_bounds__(256) void h1_combine(short* __restrict__ PQ,
                                                  const int* __restrict__ neigh_idx) {
    const int t = blockIdx.x * 256 + threadIdx.x;
    const int n = t >> 6;
    const int h = t & 63;
    if (n >= N_NODES) return;
    float p = bf2f(PQ[(size_t)n * 128 + h]);
    float s = 0.f;
#pragma unroll
    for (int i = 0; i < NUM_SAMPLES; i++) {
        const int ni = clampi(neigh_idx[n * NUM_SAMPLES + i]);
        s += bf2f(PQ[(size_t)ni * 128 + 64 + h]);
    }
    float v = p + 0.2f * s;
    v = v > 0.f ? v : 0.f;
    PQ[(size_t)n * 128 + h] = f2bf(v);
}

// Kernel C: g = concat(h1[node], 0.2*sum_s h1[neigh[node][s]]);
// h2 = relu(g @ w2^T); out = h2 @ wcls^T (fp32 out). h1 rows at PQ[n*128 + 0..63].
__global__ __launch_bounds__(256) void layer2_cls(const short* __restrict__ PQ,
                                                  const int* __restrict__ nodes_i32,
                                                  const int* __restrict__ neigh_idx,
                                                  const float* __restrict__ w2,
                                                  const float* __restrict__ wcls,
                                                  const int* __restrict__ flag,
                                                  float* __restrict__ out) {
    __shared__ float gbuf[4][128];
    __shared__ float h2buf[4][64];
    const int wave = threadIdx.x >> 6;
    const int lane = threadIdx.x & 63;
    const int b = blockIdx.x * 4 + wave;   // grid exact: b < BATCH

    const int is64 = *flag;
    const int node = clampi(nodes_i32[is64 ? 2 * b : b]);  // int64: low word holds id
    float selfv = bf2f(PQ[(size_t)node * 128 + lane]);
    float ns = 0.f;
#pragma unroll
    for (int s = 0; s < NUM_SAMPLES; s++) {
        const int ni = clampi(neigh_idx[node * NUM_SAMPLES + s]);
        ns += bf2f(PQ[(size_t)ni * 128 + lane]);
    }
    gbuf[wave][lane] = selfv;
    gbuf[wave][64 + lane] = 0.2f * ns;
    __syncthreads();

    float acc = 0.f;
#pragma unroll 8
    for (int k = 0; k < 128; k++) acc += gbuf[wave][k] * w2[lane * 128 + k];
    float h2 = acc > 0.f ? acc : 0.f;
    h2buf[wave][lane] = h2;
    __syncthreads();

    if (lane < NUM_CLASSES) {
        float o = 0.f;
#pragma unroll 8
        for (int j = 0; j < HIDDEN; j++) o += h2buf[wave][j] * wcls[lane * 64 + j];
        out[(size_t)b * NUM_CLASSES + lane] = o;
    }
}

extern "C" void kernel_launch(void* const* d_in, const int* in_sizes, int n_in,
                              void* d_out, int out_size, void* d_ws, size_t ws_size,
                              hipStream_t stream) {
    // Bind inputs by flat element count (all distinct).
    const float* feat = nullptr;      // 100000*512  = 51,200,000
    const float* w1 = nullptr;        // 64*1024     = 65,536
    const float* w2 = nullptr;        // 64*128      = 8,192
    const float* wcls = nullptr;      // 16*64       = 1,024
    const int* nodes = nullptr;       // 16,384
    const int* neigh_idx = nullptr;   // 100000*5    = 500,000
    for (int i = 0; i < n_in; i++) {
        switch (in_sizes[i]) {
            case 51200000: feat = (const float*)d_in[i]; break;
            case 65536:    w1 = (const float*)d_in[i]; break;
            case 8192:     w2 = (const float*)d_in[i]; break;
            case 1024:     wcls = (const float*)d_in[i]; break;
            case 16384:    nodes = (const int*)d_in[i]; break;
            case 500000:   neigh_idx = (const int*)d_in[i]; break;
            default: break;
        }
    }
    float* out = (float*)d_out;  // [16384,16] fp32

    // ws layout: [0..4) nodes-dtype flag; [256 ..) w1 bf16 (131072 B);
    // then PQ bf16 [100000][128] (25.6 MB).
    int* flag = (int*)d_ws;
    short* w1b = (short*)((char*)d_ws + 256);
    short* PQ  = (short*)((char*)d_ws + 256 + 64 * 1024 * sizeof(short));

    prep<<<(64 * 1024 + 255) / 256, 256, 0, stream>>>(w1, w1b, nodes, flag);
    pq_gemm<<<(N_NODES + 63) / 64, 256, 0, stream>>>(feat, w1b, PQ);
    h1_combine<<<N_NODES * 64 / 256, 256, 0, stream>>>(PQ, neigh_idx);
    layer2_cls<<<BATCH / 4, 256, 0, stream>>>(PQ, nodes, neigh_idx, w2, wcls, flag, out);
}

// Round 5
// 410.750 us; speedup vs baseline: 1.1376x; 1.1376x over previous
//
#include <hip/hip_runtime.h>
#include <hip/hip_bf16.h>

#define N_NODES 100000
#define N_FEATS 512
#define HIDDEN 64
#define NUM_SAMPLES 5
#define NUM_CLASSES 16
#define BATCH 16384

typedef __attribute__((ext_vector_type(8))) short bf16x8;
typedef __attribute__((ext_vector_type(8))) unsigned short u16x8;
typedef __attribute__((ext_vector_type(4))) float f32x4;

static __device__ __forceinline__ float bf2f(unsigned short s) {
    unsigned int u = ((unsigned int)s) << 16;
    return __builtin_bit_cast(float, u);
}
static __device__ __forceinline__ short f2bf(float v) {
    __hip_bfloat16 b = __float2bfloat16(v);
    return *reinterpret_cast<short*>(&b);
}
static __device__ __forceinline__ int clampi(int v) {
    return ((unsigned)v < (unsigned)N_NODES) ? v : 0;
}

// prep: (a) repack w1 [64][1024] fp32 into bf16 MFMA-fragment order:
// w1p[((kk*8 + nb)*64 + lane)*8 + j] = w1[h][part*512 + kk*32 + quad*8 + j]
// where l16=lane&15, quad=lane>>4, cn=nb*16+l16, h=cn&63, part=cn>>6.
// (b) detect whether `nodes` is int64 (odd int32 words all zero).
__global__ __launch_bounds__(256) void prep(const float* __restrict__ w1f,
                                            short* __restrict__ w1p,
                                            const int* __restrict__ nodes_i32,
                                            int* __restrict__ flag) {
    const int t = blockIdx.x * 256 + threadIdx.x;  // 0..65535
    if (t < 64 * 1024) {
        const int j = t & 7;
        const int lane = (t >> 3) & 63;
        const int nb = (t >> 9) & 7;
        const int kk = t >> 12;
        const int l16 = lane & 15, quad = lane >> 4;
        const int cn = nb * 16 + l16;
        const int h = cn & 63, part = cn >> 6;
        w1p[t] = f2bf(w1f[h * 1024 + part * 512 + kk * 32 + quad * 8 + j]);
    }
    if (blockIdx.x == 0 && threadIdx.x == 0) {
        int odd_nonzero = 0;
        for (int i = 0; i < 64; i++)
            if (nodes_i32[2 * i + 1] != 0) odd_nonzero++;
        *flag = (odd_nonzero == 0) ? 1 : 0;  // 1 => nodes is int64
    }
}

// Kernel A: PQ[n][c] (bf16): c<64 -> feat @ W1a^T ; c in [64,128) -> feat @ W1b^T
// A loaded fp32 direct with 1-deep prefetch; B from packed w1p (coalesced, L1-hot).
__global__ __launch_bounds__(256) void pq_gemm(const float* __restrict__ feat,
                                               const short* __restrict__ w1p,
                                               short* __restrict__ PQ) {
    const int wave = threadIdx.x >> 6;
    const int lane = threadIdx.x & 63;
    const int quad = lane >> 4;
    const int l16  = lane & 15;
    const int r0   = blockIdx.x * 64 + wave * 16;

    int rA = r0 + l16;
    if (rA >= N_NODES) rA = N_NODES - 1;

    f32x4 acc[8];
#pragma unroll
    for (int i = 0; i < 8; i++) acc[i] = (f32x4){0.f, 0.f, 0.f, 0.f};

    const float* aptr = feat + (size_t)rA * N_FEATS + quad * 8;
    const short* bptr = w1p + lane * 8;

    f32x4 a0 = *reinterpret_cast<const f32x4*>(aptr);
    f32x4 a1 = *reinterpret_cast<const f32x4*>(aptr + 4);

#pragma unroll
    for (int kk = 0; kk < 16; kk++) {
        f32x4 n0, n1;
        if (kk < 15) {  // prefetch next A chunk before the MFMA chain
            n0 = *reinterpret_cast<const f32x4*>(aptr + kk * 32 + 32);
            n1 = *reinterpret_cast<const f32x4*>(aptr + kk * 32 + 36);
        }
        bf16x8 afrag;
#pragma unroll
        for (int j = 0; j < 4; j++) { afrag[j] = f2bf(a0[j]); afrag[4 + j] = f2bf(a1[j]); }
        const short* bk = bptr + kk * 4096;  // (kk*8+nb)*512 shorts
#pragma unroll
        for (int nb = 0; nb < 8; nb++) {
            bf16x8 bfrag = *reinterpret_cast<const bf16x8*>(bk + nb * 512);
            acc[nb] = __builtin_amdgcn_mfma_f32_16x16x32_bf16(afrag, bfrag, acc[nb], 0, 0, 0);
        }
        a0 = n0; a1 = n1;
    }

    // C/D layout (16x16x32): col(N) = lane&15 -> cn, row(M) = quad*4 + reg
#pragma unroll
    for (int nb = 0; nb < 8; nb++) {
        const int cn = nb * 16 + l16;
#pragma unroll
        for (int r = 0; r < 4; r++) {
            const int row = r0 + quad * 4 + r;
            if (row < N_NODES) PQ[(size_t)row * 128 + cn] = f2bf(acc[nb][r]);
        }
    }
}

// Kernel B: h1[n][h] = relu(P[n][h] + 0.2*sum_s Q[neigh[n][s]][h]) IN-PLACE into
// PQ[n*128+h]. 8 threads per node, 16 B (8 cols) per thread. Writes cols 0..63
// only; Q reads cols 64..127 only -> race-free.
__global__ __launch_bounds__(256) void h1_combine(short* __restrict__ PQ,
                                                  const int* __restrict__ neigh_idx) {
    const int t = blockIdx.x * 256 + threadIdx.x;
    const int n = t >> 3;
    const int sub = t & 7;
    if (n >= N_NODES) return;

    u16x8 pv = *reinterpret_cast<const u16x8*>(PQ + (size_t)n * 128 + sub * 8);
    float s[8];
#pragma unroll
    for (int j = 0; j < 8; j++) s[j] = 0.f;
#pragma unroll
    for (int i = 0; i < NUM_SAMPLES; i++) {
        const int ni = clampi(neigh_idx[n * NUM_SAMPLES + i]);
        u16x8 qv = *reinterpret_cast<const u16x8*>(PQ + (size_t)ni * 128 + 64 + sub * 8);
#pragma unroll
        for (int j = 0; j < 8; j++) s[j] += bf2f(qv[j]);
    }
    u16x8 ov;
#pragma unroll
    for (int j = 0; j < 8; j++) {
        float v = bf2f(pv[j]) + 0.2f * s[j];
        v = v > 0.f ? v : 0.f;
        ov[j] = (unsigned short)f2bf(v);
    }
    *reinterpret_cast<u16x8*>(PQ + (size_t)n * 128 + sub * 8) = ov;
}

// Kernel C: g = concat(h1[node], 0.2*sum_s h1[neigh[node][s]]);
// h2 = relu(g @ w2^T); out = h2 @ wcls^T (fp32). h1 rows at PQ[n*128 + 0..63].
__global__ __launch_bounds__(256) void layer2_cls(const short* __restrict__ PQ,
                                                  const int* __restrict__ nodes_i32,
                                                  const int* __restrict__ neigh_idx,
                                                  const float* __restrict__ w2,
                                                  const float* __restrict__ wcls,
                                                  const int* __restrict__ flag,
                                                  float* __restrict__ out) {
    __shared__ float gbuf[4][128];
    __shared__ float h2buf[4][64];
    const int wave = threadIdx.x >> 6;
    const int lane = threadIdx.x & 63;
    const int b = blockIdx.x * 4 + wave;   // grid exact: b < BATCH

    const int is64 = *flag;
    const int node = clampi(nodes_i32[is64 ? 2 * b : b]);
    float selfv = bf2f((unsigned short)PQ[(size_t)node * 128 + lane]);
    float ns = 0.f;
#pragma unroll
    for (int s = 0; s < NUM_SAMPLES; s++) {
        const int ni = clampi(neigh_idx[node * NUM_SAMPLES + s]);
        ns += bf2f((unsigned short)PQ[(size_t)ni * 128 + lane]);
    }
    gbuf[wave][lane] = selfv;
    gbuf[wave][64 + lane] = 0.2f * ns;
    __syncthreads();

    const f32x4* w2r = reinterpret_cast<const f32x4*>(w2 + lane * 128);
    const f32x4* gr  = reinterpret_cast<const f32x4*>(&gbuf[wave][0]);
    float acc = 0.f;
#pragma unroll
    for (int k = 0; k < 32; k++) {
        f32x4 g = gr[k], w = w2r[k];
        acc += g[0] * w[0] + g[1] * w[1] + g[2] * w[2] + g[3] * w[3];
    }
    float h2 = acc > 0.f ? acc : 0.f;
    h2buf[wave][lane] = h2;
    __syncthreads();

    if (lane < NUM_CLASSES) {
        const f32x4* wcr = reinterpret_cast<const f32x4*>(wcls + lane * 64);
        const f32x4* hr  = reinterpret_cast<const f32x4*>(&h2buf[wave][0]);
        float o = 0.f;
#pragma unroll
        for (int k = 0; k < 16; k++) {
            f32x4 h = hr[k], w = wcr[k];
            o += h[0] * w[0] + h[1] * w[1] + h[2] * w[2] + h[3] * w[3];
        }
        out[(size_t)b * NUM_CLASSES + lane] = o;
    }
}

extern "C" void kernel_launch(void* const* d_in, const int* in_sizes, int n_in,
                              void* d_out, int out_size, void* d_ws, size_t ws_size,
                              hipStream_t stream) {
    // Bind inputs by flat element count (all distinct).
    const float* feat = nullptr;      // 100000*512  = 51,200,000
    const float* w1 = nullptr;        // 64*1024     = 65,536
    const float* w2 = nullptr;        // 64*128      = 8,192
    const float* wcls = nullptr;      // 16*64       = 1,024
    const int* nodes = nullptr;       // 16,384
    const int* neigh_idx = nullptr;   // 100000*5    = 500,000
    for (int i = 0; i < n_in; i++) {
        switch (in_sizes[i]) {
            case 51200000: feat = (const float*)d_in[i]; break;
            case 65536:    w1 = (const float*)d_in[i]; break;
            case 8192:     w2 = (const float*)d_in[i]; break;
            case 1024:     wcls = (const float*)d_in[i]; break;
            case 16384:    nodes = (const int*)d_in[i]; break;
            case 500000:   neigh_idx = (const int*)d_in[i]; break;
            default: break;
        }
    }
    float* out = (float*)d_out;  // [16384,16] fp32

    // ws layout: [0..4) nodes-dtype flag; [256 ..) packed w1 bf16 (131072 B);
    // then PQ bf16 [100000][128] (25.6 MB).
    int* flag = (int*)d_ws;
    short* w1p = (short*)((char*)d_ws + 256);
    short* PQ  = (short*)((char*)d_ws + 256 + 64 * 1024 * sizeof(short));

    prep<<<256, 256, 0, stream>>>(w1, w1p, nodes, flag);
    pq_gemm<<<(N_NODES + 63) / 64, 256, 0, stream>>>(feat, w1p, PQ);
    h1_combine<<<(N_NODES * 8 + 255) / 256, 256, 0, stream>>>(PQ, neigh_idx);
    layer2_cls<<<BATCH / 4, 256, 0, stream>>>(PQ, nodes, neigh_idx, w2, wcls, flag, out);
}

// Round 6
// 369.698 us; speedup vs baseline: 1.2639x; 1.1110x over previous
//
#include <hip/hip_runtime.h>
#include <hip/hip_bf16.h>

#define N_NODES 100000
#define N_FEATS 512
#define HIDDEN 64
#define NUM_SAMPLES 5
#define NUM_CLASSES 16
#define BATCH 16384

typedef __attribute__((ext_vector_type(8))) short bf16x8;
typedef __attribute__((ext_vector_type(8))) unsigned short u16x8;
typedef __attribute__((ext_vector_type(4))) float f32x4;

static __device__ __forceinline__ float bf2f(unsigned short s) {
    unsigned int u = ((unsigned int)s) << 16;
    return __builtin_bit_cast(float, u);
}
static __device__ __forceinline__ short f2bf(float v) {
    __hip_bfloat16 b = __float2bfloat16(v);
    return *reinterpret_cast<short*>(&b);
}
static __device__ __forceinline__ int clampi(int v) {
    return ((unsigned)v < (unsigned)N_NODES) ? v : 0;
}

// prep: (a) repack w1 [64][1024] fp32 into bf16 MFMA-fragment order:
// w1p[((kk*8 + nb)*64 + lane)*8 + j] = w1[h][part*512 + kk*32 + quad*8 + j]
// (b) detect whether `nodes` is int64 (odd int32 words all zero).
__global__ __launch_bounds__(256) void prep(const float* __restrict__ w1f,
                                            short* __restrict__ w1p,
                                            const int* __restrict__ nodes_i32,
                                            int* __restrict__ flag) {
    const int t = blockIdx.x * 256 + threadIdx.x;  // 0..65535
    if (t < 64 * 1024) {
        const int j = t & 7;
        const int lane = (t >> 3) & 63;
        const int nb = (t >> 9) & 7;
        const int kk = t >> 12;
        const int l16 = lane & 15, quad = lane >> 4;
        const int cn = nb * 16 + l16;
        const int h = cn & 63, part = cn >> 6;
        w1p[t] = f2bf(w1f[h * 1024 + part * 512 + kk * 32 + quad * 8 + j]);
    }
    if (blockIdx.x == 0 && threadIdx.x == 0) {
        int odd_nonzero = 0;
        for (int i = 0; i < 64; i++)
            if (nodes_i32[2 * i + 1] != 0) odd_nonzero++;
        *flag = (odd_nonzero == 0) ? 1 : 0;  // 1 => nodes is int64
    }
}

// Kernel A: PQ[n][c] (bf16): c<64 -> feat @ W1a^T ; c in [64,128) -> feat @ W1b^T
// K-loop grouped 4x4: prefetch next group's 8x16B A-loads (8 outstanding vmem/wave)
// before the MFMA chain. B from packed w1p (wave-coalesced 1KB loads, L1/L2-hot).
__global__ __launch_bounds__(256) void pq_gemm(const float* __restrict__ feat,
                                               const short* __restrict__ w1p,
                                               short* __restrict__ PQ) {
    const int wave = threadIdx.x >> 6;
    const int lane = threadIdx.x & 63;
    const int quad = lane >> 4;
    const int l16  = lane & 15;
    const int r0   = blockIdx.x * 64 + wave * 16;

    int rA = r0 + l16;
    if (rA >= N_NODES) rA = N_NODES - 1;

    const float* aptr = feat + (size_t)rA * N_FEATS + quad * 8;
    const short* bbase = w1p + lane * 8;

    f32x4 buf[2][8];
#pragma unroll
    for (int c = 0; c < 4; c++) {
        buf[0][2 * c]     = *reinterpret_cast<const f32x4*>(aptr + c * 32);
        buf[0][2 * c + 1] = *reinterpret_cast<const f32x4*>(aptr + c * 32 + 4);
    }

    f32x4 acc[8];
#pragma unroll
    for (int i = 0; i < 8; i++) acc[i] = (f32x4){0.f, 0.f, 0.f, 0.f};

#pragma unroll
    for (int g = 0; g < 4; g++) {
        const int cur = g & 1;
        if (g < 3) {  // prefetch next group's 4 k-steps (8 x 16B loads in flight)
#pragma unroll
            for (int c = 0; c < 4; c++) {
                buf[cur ^ 1][2 * c]     = *reinterpret_cast<const f32x4*>(aptr + (g + 1) * 128 + c * 32);
                buf[cur ^ 1][2 * c + 1] = *reinterpret_cast<const f32x4*>(aptr + (g + 1) * 128 + c * 32 + 4);
            }
        }
#pragma unroll
        for (int kk2 = 0; kk2 < 4; kk2++) {
            const int kk = g * 4 + kk2;
            bf16x8 afrag;
#pragma unroll
            for (int j = 0; j < 4; j++) {
                afrag[j]     = f2bf(buf[cur][2 * kk2][j]);
                afrag[4 + j] = f2bf(buf[cur][2 * kk2 + 1][j]);
            }
            const short* bk = bbase + kk * 4096;
#pragma unroll
            for (int nb = 0; nb < 8; nb++) {
                bf16x8 bfrag = *reinterpret_cast<const bf16x8*>(bk + nb * 512);
                acc[nb] = __builtin_amdgcn_mfma_f32_16x16x32_bf16(afrag, bfrag, acc[nb], 0, 0, 0);
            }
        }
    }

    // C/D layout (16x16x32): col(N) = lane&15 -> cn, row(M) = quad*4 + reg
#pragma unroll
    for (int nb = 0; nb < 8; nb++) {
        const int cn = nb * 16 + l16;
#pragma unroll
        for (int r = 0; r < 4; r++) {
            const int row = r0 + quad * 4 + r;
            if (row < N_NODES) PQ[(size_t)row * 128 + cn] = f2bf(acc[nb][r]);
        }
    }
}

// Kernel B: h1[n][h] = relu(P[n][h] + 0.2*sum_s Q[neigh[n][s]][h]) IN-PLACE into
// PQ[n*128+h]. 8 threads per node, 16B per thread. Writes cols 0..63 only;
// Q reads cols 64..127 only -> race-free.
__global__ __launch_bounds__(256) void h1_combine(short* __restrict__ PQ,
                                                  const int* __restrict__ neigh_idx) {
    const int t = blockIdx.x * 256 + threadIdx.x;
    const int n = t >> 3;
    const int sub = t & 7;
    if (n >= N_NODES) return;

    u16x8 pv = *reinterpret_cast<const u16x8*>(PQ + (size_t)n * 128 + sub * 8);
    float s[8];
#pragma unroll
    for (int j = 0; j < 8; j++) s[j] = 0.f;
#pragma unroll
    for (int i = 0; i < NUM_SAMPLES; i++) {
        const int ni = clampi(neigh_idx[n * NUM_SAMPLES + i]);
        u16x8 qv = *reinterpret_cast<const u16x8*>(PQ + (size_t)ni * 128 + 64 + sub * 8);
#pragma unroll
        for (int j = 0; j < 8; j++) s[j] += bf2f(qv[j]);
    }
    u16x8 ov;
#pragma unroll
    for (int j = 0; j < 8; j++) {
        float v = bf2f(pv[j]) + 0.2f * s[j];
        v = v > 0.f ? v : 0.f;
        ov[j] = (unsigned short)f2bf(v);
    }
    *reinterpret_cast<u16x8*>(PQ + (size_t)n * 128 + sub * 8) = ov;
}

// Kernel C: 16 batch items per block (4 per wave). g = concat(h1[node],
// 0.2*sum_s h1[neigh[node][s]]); h2 = relu(g @ w2^T); out = h2 @ wcls^T (fp32).
// w2 loads amortized over 4 items; gbuf/h2buf LDS reads are same-address
// broadcasts (conflict-free).
__global__ __launch_bounds__(256) void layer2_cls(const short* __restrict__ PQ,
                                                  const int* __restrict__ nodes_i32,
                                                  const int* __restrict__ neigh_idx,
                                                  const float* __restrict__ w2,
                                                  const float* __restrict__ wcls,
                                                  const int* __restrict__ flag,
                                                  float* __restrict__ out) {
    __shared__ float gbuf[16][128];
    __shared__ float h2buf[16][64];
    const int wave = threadIdx.x >> 6;
    const int lane = threadIdx.x & 63;
    const int is64 = *flag;
    const int b0 = blockIdx.x * 16;

#pragma unroll
    for (int it = 0; it < 4; it++) {
        const int item = wave * 4 + it;
        const int b = b0 + item;
        const int node = clampi(nodes_i32[is64 ? 2 * b : b]);
        float selfv = bf2f((unsigned short)PQ[(size_t)node * 128 + lane]);
        float ns = 0.f;
#pragma unroll
        for (int s = 0; s < NUM_SAMPLES; s++) {
            const int ni = clampi(neigh_idx[node * NUM_SAMPLES + s]);
            ns += bf2f((unsigned short)PQ[(size_t)ni * 128 + lane]);
        }
        gbuf[item][lane] = selfv;
        gbuf[item][64 + lane] = 0.2f * ns;
    }
    __syncthreads();

    float acc[4] = {0.f, 0.f, 0.f, 0.f};
    const f32x4* w2r = reinterpret_cast<const f32x4*>(w2 + lane * 128);
#pragma unroll 8
    for (int k = 0; k < 32; k++) {
        f32x4 w = w2r[k];
#pragma unroll
        for (int it = 0; it < 4; it++) {
            f32x4 g = *reinterpret_cast<const f32x4*>(&gbuf[wave * 4 + it][k * 4]);
            acc[it] += g[0] * w[0] + g[1] * w[1] + g[2] * w[2] + g[3] * w[3];
        }
    }
#pragma unroll
    for (int it = 0; it < 4; it++) {
        float h2 = acc[it] > 0.f ? acc[it] : 0.f;
        h2buf[wave * 4 + it][lane] = h2;
    }
    __syncthreads();

    if (lane < NUM_CLASSES) {
        const f32x4* wcr = reinterpret_cast<const f32x4*>(wcls + lane * 64);
#pragma unroll
        for (int it = 0; it < 4; it++) {
            const int item = wave * 4 + it;
            const f32x4* hr = reinterpret_cast<const f32x4*>(&h2buf[item][0]);
            float o = 0.f;
#pragma unroll
            for (int k = 0; k < 16; k++) {
                f32x4 h = hr[k], w = wcr[k];
                o += h[0] * w[0] + h[1] * w[1] + h[2] * w[2] + h[3] * w[3];
            }
            out[(size_t)(b0 + item) * NUM_CLASSES + lane] = o;
        }
    }
}

extern "C" void kernel_launch(void* const* d_in, const int* in_sizes, int n_in,
                              void* d_out, int out_size, void* d_ws, size_t ws_size,
                              hipStream_t stream) {
    const float* feat = nullptr;      // 100000*512  = 51,200,000
    const float* w1 = nullptr;        // 64*1024     = 65,536
    const float* w2 = nullptr;        // 64*128      = 8,192
    const float* wcls = nullptr;      // 16*64       = 1,024
    const int* nodes = nullptr;       // 16,384
    const int* neigh_idx = nullptr;   // 100000*5    = 500,000
    for (int i = 0; i < n_in; i++) {
        switch (in_sizes[i]) {
            case 51200000: feat = (const float*)d_in[i]; break;
            case 65536:    w1 = (const float*)d_in[i]; break;
            case 8192:     w2 = (const float*)d_in[i]; break;
            case 1024:     wcls = (const float*)d_in[i]; break;
            case 16384:    nodes = (const int*)d_in[i]; break;
            case 500000:   neigh_idx = (const int*)d_in[i]; break;
            default: break;
        }
    }
    float* out = (float*)d_out;  // [16384,16] fp32

    // ws layout: [0..4) nodes-dtype flag; [256 ..) packed w1 bf16 (131072 B);
    // then PQ bf16 [100000][128] (25.6 MB).
    int* flag = (int*)d_ws;
    short* w1p = (short*)((char*)d_ws + 256);
    short* PQ  = (short*)((char*)d_ws + 256 + 64 * 1024 * sizeof(short));

    prep<<<256, 256, 0, stream>>>(w1, w1p, nodes, flag);
    pq_gemm<<<(N_NODES + 63) / 64, 256, 0, stream>>>(feat, w1p, PQ);
    h1_combine<<<(N_NODES * 8 + 255) / 256, 256, 0, stream>>>(PQ, neigh_idx);
    layer2_cls<<<BATCH / 16, 256, 0, stream>>>(PQ, nodes, neigh_idx, w2, wcls, flag, out);
}